// Round 6
// baseline (131.317 us; speedup 1.0000x reference)
//
#include <hip/hip_runtime.h>
#include <hip/hip_cooperative_groups.h>

namespace cg = cooperative_groups;

// Problem shape (fixed by the reference setup)
#define TT 512
#define BB 32
#define FF 256
#define LL 8
#define NCHAIN (BB * FF * LL)   // 65536 chains
#define NGROUP (NCHAIN / 4)     // 16384 float4 groups (4 consecutive l's)
#define NCHUNK 16
#define TC (TT / NCHUNK)        // 32 steps per chunk
#define NUNIT (NCHUNK * 64)     // 1024 block-units

typedef float f32x4 __attribute__((ext_vector_type(4)));

// Unit decomposition (shared by all kernels): unit u -> chunk = u>>6,
// blockLocal = u&63; b = blockLocal>>1 (unit-uniform -> resets is a scalar
// broadcast); idx = ((blockLocal&1)<<8)|tid; f = idx>>1; h = idx&1;
// group g = (b<<9)|idx. Consecutive lanes -> consecutive 16B slots -> 1KiB/wave.

// Fused cooperative kernel: phase A computes per-chunk affine summaries
// (A = prod a_t, E = zero-init scan end); grid.sync(); phase B folds the
// carry through preceding chunks (<=15 L2-hot 32B reads/thread), then
// replays the chunk writing every step. Same block handles the same unit in
// both phases -> features L2-hot for the replay.
__global__ __launch_bounds__(256, 4) void fused_coop(
    const float* __restrict__ features,  // [T,B,F]
    const int*   __restrict__ resets,    // [T,B]
    const float* __restrict__ carry,     // [B,F,L]
    const float* __restrict__ lambdas,   // [L]
    f32x4*       __restrict__ wsA,       // [NCHUNK][NGROUP]
    f32x4*       __restrict__ wsE,       // [NCHUNK][NGROUP]
    f32x4*       __restrict__ out4)      // [NGROUP] final, then [T][NGROUP]
{
    cg::grid_group grid = cg::this_grid();

    // ---- Phase A: chunk summaries ----
    for (int u = blockIdx.x; u < NUNIT; u += gridDim.x) {
        const int chunk      = u >> 6;
        const int blockLocal = u & 63;
        const int b   = blockLocal >> 1;
        const int idx = ((blockLocal & 1) << 8) | threadIdx.x;
        const int f   = idx >> 1;
        const int h   = idx & 1;
        const int g   = (b << 9) | idx;

        const f32x4 lam  = ((const f32x4*)lambdas)[h];
        const f32x4 onem = 1.0f - lam;
        const int   t0   = chunk * TC;

        const float* fptr = features + (size_t)t0 * (BB * FF) + b * FF + f;
        const int*   rptr = resets + (size_t)t0 * BB + b;

        f32x4 A = 1.0f, E = 0.0f;
        #pragma unroll 8
        for (int t = 0; t < TC; ++t) {
            const float x = fptr[(size_t)t * (BB * FF)];
            const int   r = rptr[(size_t)t * BB];
            #pragma unroll
            for (int j = 0; j < 4; ++j) {
                const float Av = A[j] * lam[j];
                const float Ev = fmaf(lam[j], E[j], onem[j] * x);
                A[j] = r ? 0.0f : Av;
                E[j] = r ? x : Ev;
            }
        }
        wsA[(size_t)chunk * NGROUP + g] = A;
        wsE[(size_t)chunk * NGROUP + g] = E;
    }

    grid.sync();

    // ---- Phase B: fold + replay + write ----
    for (int u = blockIdx.x; u < NUNIT; u += gridDim.x) {
        const int chunk      = u >> 6;
        const int blockLocal = u & 63;
        const int b   = blockLocal >> 1;
        const int idx = ((blockLocal & 1) << 8) | threadIdx.x;
        const int f   = idx >> 1;
        const int h   = idx & 1;
        const int g   = (b << 9) | idx;

        const f32x4 lam  = ((const f32x4*)lambdas)[h];
        const f32x4 onem = 1.0f - lam;
        const int   t0   = chunk * TC;

        // Fold carry through chunks [0, chunk) -> true initial state.
        f32x4 s = ((const f32x4*)carry)[g];
        for (int cc = 0; cc < chunk; ++cc) {
            const f32x4 Ac = wsA[(size_t)cc * NGROUP + g];
            const f32x4 Ec = wsE[(size_t)cc * NGROUP + g];
            #pragma unroll
            for (int j = 0; j < 4; ++j) s[j] = fmaf(Ac[j], s[j], Ec[j]);
        }

        const float* fptr = features + (size_t)t0 * (BB * FF) + b * FF + f;
        const int*   rptr = resets + (size_t)t0 * BB + b;
        f32x4*       yptr = out4 + NGROUP + (size_t)t0 * NGROUP + g;

        #pragma unroll 4
        for (int t = 0; t < TC; ++t) {
            const float x = fptr[(size_t)t * (BB * FF)];
            const int   r = rptr[(size_t)t * BB];
            #pragma unroll
            for (int j = 0; j < 4; ++j) {
                const float v = fmaf(lam[j], s[j], onem[j] * x);
                s[j] = r ? x : v;
            }
            __builtin_nontemporal_store(s, yptr + (size_t)t * NGROUP);
        }

        if (chunk == NCHUNK - 1) out4[g] = s;  // final_trace (first in concat)
    }
}

// ---- Non-cooperative fallback pair (round-3 structure, measured 37.5 us) ----
__global__ __launch_bounds__(256) void phase1_vec(
    const float* __restrict__ features, const int* __restrict__ resets,
    const float* __restrict__ lambdas,
    f32x4* __restrict__ wsA, f32x4* __restrict__ wsE)
{
    const int chunk      = blockIdx.x >> 6;
    const int blockLocal = blockIdx.x & 63;
    const int b   = blockLocal >> 1;
    const int idx = ((blockLocal & 1) << 8) | threadIdx.x;
    const int f   = idx >> 1;
    const int h   = idx & 1;
    const int g   = (b << 9) | idx;

    const f32x4 lam  = ((const f32x4*)lambdas)[h];
    const f32x4 onem = 1.0f - lam;
    const int   t0   = chunk * TC;

    const float* fptr = features + (size_t)t0 * (BB * FF) + b * FF + f;
    const int*   rptr = resets + (size_t)t0 * BB + b;

    f32x4 A = 1.0f, E = 0.0f;
    #pragma unroll 8
    for (int t = 0; t < TC; ++t) {
        const float x = fptr[(size_t)t * (BB * FF)];
        const int   r = rptr[(size_t)t * BB];
        #pragma unroll
        for (int j = 0; j < 4; ++j) {
            const float Av = A[j] * lam[j];
            const float Ev = fmaf(lam[j], E[j], onem[j] * x);
            A[j] = r ? 0.0f : Av;
            E[j] = r ? x : Ev;
        }
    }
    wsA[(size_t)chunk * NGROUP + g] = A;
    wsE[(size_t)chunk * NGROUP + g] = E;
}

__global__ __launch_bounds__(256) void phase2_vec(
    const float* __restrict__ features, const int* __restrict__ resets,
    const float* __restrict__ carry, const float* __restrict__ lambdas,
    const f32x4* __restrict__ wsA, const f32x4* __restrict__ wsE,
    f32x4* __restrict__ out4)
{
    const int chunk      = blockIdx.x >> 6;
    const int blockLocal = blockIdx.x & 63;
    const int b   = blockLocal >> 1;
    const int idx = ((blockLocal & 1) << 8) | threadIdx.x;
    const int f   = idx >> 1;
    const int h   = idx & 1;
    const int g   = (b << 9) | idx;

    const f32x4 lam  = ((const f32x4*)lambdas)[h];
    const f32x4 onem = 1.0f - lam;
    const int   t0   = chunk * TC;

    f32x4 s = ((const f32x4*)carry)[g];
    for (int cc = 0; cc < chunk; ++cc) {
        const f32x4 Ac = wsA[(size_t)cc * NGROUP + g];
        const f32x4 Ec = wsE[(size_t)cc * NGROUP + g];
        #pragma unroll
        for (int j = 0; j < 4; ++j) s[j] = fmaf(Ac[j], s[j], Ec[j]);
    }

    const float* fptr = features + (size_t)t0 * (BB * FF) + b * FF + f;
    const int*   rptr = resets + (size_t)t0 * BB + b;
    f32x4*       yptr = out4 + NGROUP + (size_t)t0 * NGROUP + g;

    #pragma unroll 4
    for (int t = 0; t < TC; ++t) {
        const float x = fptr[(size_t)t * (BB * FF)];
        const int   r = rptr[(size_t)t * BB];
        #pragma unroll
        for (int j = 0; j < 4; ++j) {
            const float v = fmaf(lam[j], s[j], onem[j] * x);
            s[j] = r ? x : v;
        }
        __builtin_nontemporal_store(s, yptr + (size_t)t * NGROUP);
    }

    if (chunk == NCHUNK - 1) out4[g] = s;
}

// Tiny-ws fallback (round-1 single-pass kernel, known correct).
__global__ __launch_bounds__(256) void trace_rnn_fallback(
    const float* __restrict__ features, const int* __restrict__ resets,
    const float* __restrict__ carry, const float* __restrict__ lambdas,
    float* __restrict__ out)
{
    const int b  = blockIdx.x >> 3;
    const int fl = ((blockIdx.x & 7) << 8) | threadIdx.x;
    const int f  = fl >> 3;
    const int l  = fl & 7;
    const int gid = (b << 11) | fl;

    const float lam  = lambdas[l];
    const float onem = 1.0f - lam;

    float trace = carry[gid];
    const float* fptr = features + b * FF + f;
    const int*   rptr = resets + b;
    float*       yptr = out + NCHAIN + gid;

    #pragma unroll 4
    for (int t = 0; t < TT; ++t) {
        const float x = fptr[(size_t)t * (BB * FF)];
        const int   r = rptr[(size_t)t * BB];
        const float v = fmaf(lam, trace, onem * x);
        trace = r ? x : v;
        yptr[(size_t)t * NCHAIN] = trace;
    }
    out[gid] = trace;
}

extern "C" void kernel_launch(void* const* d_in, const int* in_sizes, int n_in,
                              void* d_out, int out_size, void* d_ws, size_t ws_size,
                              hipStream_t stream) {
    const float* features = (const float*)d_in[0];
    const int*   resets   = (const int*)d_in[1];
    const float* carry    = (const float*)d_in[2];
    const float* lambdas  = (const float*)d_in[3];
    float* out = (float*)d_out;

    const size_t ws_need = (size_t)2 * NCHUNK * NGROUP * sizeof(f32x4);  // 8 MB
    if (ws_size < ws_need) {
        trace_rnn_fallback<<<NCHAIN / 256, 256, 0, stream>>>(
            features, resets, carry, lambdas, out);
        return;
    }

    f32x4* wsA  = (f32x4*)d_ws;
    f32x4* wsE  = wsA + (size_t)NCHUNK * NGROUP;
    f32x4* out4 = (f32x4*)out;

    // Co-residency: __launch_bounds__(256,4) guarantees >=4 blocks/CU
    // (1024 on 256 CUs). Query to be safe; block-stride covers cap < NUNIT.
    int blocksPerCU = 0;
    hipError_t qerr = hipOccupancyMaxActiveBlocksPerMultiprocessor(
        &blocksPerCU, fused_coop, 256, 0);

    bool coop_ok = (qerr == hipSuccess && blocksPerCU > 0);
    if (coop_ok) {
        int grid = blocksPerCU * 256;  // 256 CUs on MI355X
        if (grid > NUNIT) grid = NUNIT;
        void* args[] = {(void*)&features, (void*)&resets, (void*)&carry,
                        (void*)&lambdas,  (void*)&wsA,    (void*)&wsE,
                        (void*)&out4};
        hipError_t lerr = hipLaunchCooperativeKernel(
            fused_coop, dim3(grid), dim3(256), args, 0, stream);
        if (lerr == hipSuccess) return;
    }

    // Fallback: round-3 two-kernel path (measured 37.5 us).
    const int grid = NUNIT;
    phase1_vec<<<grid, 256, 0, stream>>>(features, resets, lambdas, wsA, wsE);
    phase2_vec<<<grid, 256, 0, stream>>>(features, resets, carry, lambdas,
                                         wsA, wsE, out4);
}

// Round 7
// 46.033 us; speedup vs baseline: 2.8527x; 2.8527x over previous
//
#include <hip/hip_runtime.h>

// Problem shape (fixed by the reference setup)
#define TT 512
#define BB 32
#define FF 256
#define LL 8
#define NCHAIN (BB * FF * LL)   // 65536 chains
#define NGROUP (NCHAIN / 4)     // 16384 float4 groups (4 consecutive l's)
#define NC 16                   // chunks per block (covers all of T)
#define TC (TT / NC)            // 32 steps per chunk
#define GB 64                   // float4-groups per block
#define NBLOCK (NGROUP / GB)    // 256 blocks

typedef float f32x4 __attribute__((ext_vector_type(4)));

// One block owns a 64-group chain slice for the WHOLE sequence:
//   1024 threads = 16 chunks (tid>>6, wave-uniform) x 64 groups (tid&63).
//   b = blockIdx>>3 (block-uniform -> resets scalar-broadcast), fblk = blockIdx&7.
//   idx = (fblk<<6)|gl; f = idx>>1; h = idx&1; g = (b<<9)|idx.
// Wave = 64 consecutive groups of ONE chunk -> every ys store is 64x16B = 1KiB
// contiguous; feature loads are 32 consecutive floats/wave (2 lanes/addr).
//
// Phase A: scan own chunk from s0=0, computing the affine summary
//   (A = prod a_t, E = zero-init scan end), stashing x in registers (full
//   unroll -> static indices) and resets in a bitmask. (A,E) -> LDS.
// __syncthreads(); fold carry through preceding chunks from LDS (<=15 FMAs).
// Phase B: replay from registers only, nontemporal-store every step.
__global__ __launch_bounds__(1024, 4) void trace_rnn_fused(
    const float* __restrict__ features,  // [T,B,F]
    const int*   __restrict__ resets,    // [T,B]
    const float* __restrict__ carry,     // [B,F,L]
    const float* __restrict__ lambdas,   // [L]
    f32x4*       __restrict__ out4)      // [NGROUP] final, then [T][NGROUP] ys
{
    __shared__ f32x4 sA[NC][GB];   // 16 KB
    __shared__ f32x4 sE[NC][GB];   // 16 KB

    const int b    = blockIdx.x >> 3;
    const int fblk = blockIdx.x & 7;
    const int c    = threadIdx.x >> 6;   // chunk, wave-uniform
    const int gl   = threadIdx.x & 63;
    const int idx  = (fblk << 6) | gl;   // 0..511
    const int f    = idx >> 1;
    const int h    = idx & 1;
    const int g    = (b << 9) | idx;

    const f32x4 lam  = ((const f32x4*)lambdas)[h];
    const f32x4 onem = 1.0f - lam;
    const int   t0   = c * TC;

    const float* fptr = features + (size_t)t0 * (BB * FF) + b * FF + f;
    const int*   rptr = resets + (size_t)t0 * BB + b;

    // ---- Phase A: chunk summary + register stash ----
    float    xs[TC];
    unsigned rmask = 0;
    f32x4 A = 1.0f, E = 0.0f;
    #pragma unroll
    for (int t = 0; t < TC; ++t) {
        const float x = fptr[(size_t)t * (BB * FF)];
        const int   r = rptr[(size_t)t * BB];
        xs[t] = x;
        rmask |= (unsigned)(r != 0) << t;
        #pragma unroll
        for (int j = 0; j < 4; ++j) {
            const float Av = A[j] * lam[j];
            const float Ev = fmaf(lam[j], E[j], onem[j] * x);
            A[j] = r ? 0.0f : Av;
            E[j] = r ? x : Ev;
        }
    }
    sA[c][gl] = A;
    sE[c][gl] = E;

    // carry load issued before the barrier to overlap its latency
    f32x4 s = ((const f32x4*)carry)[g];
    __syncthreads();

    // ---- Fold: true initial state for this chunk (LDS-resident) ----
    for (int cc = 0; cc < c; ++cc) {   // trip count wave-uniform
        const f32x4 Ac = sA[cc][gl];
        const f32x4 Ec = sE[cc][gl];
        #pragma unroll
        for (int j = 0; j < 4; ++j) s[j] = fmaf(Ac[j], s[j], Ec[j]);
    }

    // ---- Phase B: register replay + streaming writes ----
    f32x4* yptr = out4 + NGROUP + (size_t)t0 * NGROUP + g;
    #pragma unroll
    for (int t = 0; t < TC; ++t) {
        const float x = xs[t];
        const bool  r = (rmask >> t) & 1u;
        #pragma unroll
        for (int j = 0; j < 4; ++j) {
            const float v = fmaf(lam[j], s[j], onem[j] * x);
            s[j] = r ? x : v;
        }
        __builtin_nontemporal_store(s, yptr + (size_t)t * NGROUP);
    }

    // final_trace (FIRST output in the concatenation)
    if (c == NC - 1) out4[g] = s;
}

extern "C" void kernel_launch(void* const* d_in, const int* in_sizes, int n_in,
                              void* d_out, int out_size, void* d_ws, size_t ws_size,
                              hipStream_t stream) {
    const float* features = (const float*)d_in[0];
    const int*   resets   = (const int*)d_in[1];
    const float* carry    = (const float*)d_in[2];
    const float* lambdas  = (const float*)d_in[3];
    f32x4* out4 = (f32x4*)d_out;

    trace_rnn_fused<<<NBLOCK, 1024, 0, stream>>>(
        features, resets, carry, lambdas, out4);
}

// Round 8
// 28.431 us; speedup vs baseline: 4.6188x; 1.6191x over previous
//
#include <hip/hip_runtime.h>

// Problem shape (fixed by the reference setup)
#define TT 512
#define BB 32
#define FF 256
#define LL 8
#define NCHAIN (BB * FF * LL)   // 65536 chains
#define NGROUP (NCHAIN / 4)     // 16384 float4 groups (4 consecutive l's)
#define NCHUNK 32
#define TC (TT / NCHUNK)        // 16 steps per chunk

typedef float f32x4 __attribute__((ext_vector_type(4)));

// Single-pass lookback kernel. Block unit: (chunk, b, half-of-f).
//   chunk = blockIdx>>6 (block-uniform); blockLocal = blockIdx&63;
//   b = blockLocal>>1 (block-uniform -> resets scalar-broadcast, and all
//   reset-dependent control flow is wave-uniform);
//   idx = ((blockLocal&1)<<8)|tid; f = idx>>1; h = idx&1; g = (b<<9)|idx.
// Entering state: scan resets backward from t0-1 for the most recent reset
// (expected ~2 steps at p=0.5). State after a reset step t_r is exactly
// x[t_r], so replay the reset-free gap (t_r, t0) and go. If no reset ever
// occurred (never for this data, but handled exactly): replay from carry.
__global__ __launch_bounds__(256) void trace_rnn_lookback(
    const float* __restrict__ features,  // [T,B,F]
    const int*   __restrict__ resets,    // [T,B]
    const float* __restrict__ carry,     // [B,F,L]
    const float* __restrict__ lambdas,   // [L]
    f32x4*       __restrict__ out4)      // [NGROUP] final, then [T][NGROUP] ys
{
    const int chunk      = blockIdx.x >> 6;
    const int blockLocal = blockIdx.x & 63;
    const int b   = blockLocal >> 1;
    const int idx = ((blockLocal & 1) << 8) | threadIdx.x;
    const int f   = idx >> 1;
    const int h   = idx & 1;
    const int g   = (b << 9) | idx;

    const f32x4 lam  = ((const f32x4*)lambdas)[h];
    const f32x4 onem = 1.0f - lam;
    const int   t0   = chunk * TC;

    // ---- Entering state for this chunk (state after step t0-1) ----
    f32x4 s;
    if (chunk == 0) {
        s = ((const f32x4*)carry)[g];
    } else {
        int tr = t0 - 1;                      // wave-uniform backward scan
        while (tr >= 0 && resets[(size_t)tr * BB + b] == 0) --tr;
        int tstart;
        if (tr < 0) {
            s = ((const f32x4*)carry)[g];     // no reset in prefix: from carry
            tstart = 0;
        } else {
            const float xr = features[(size_t)tr * (BB * FF) + b * FF + f];
            s = xr;                           // state after reset step == x
            tstart = tr + 1;
        }
        // Replay (reset-free by construction) gap [tstart, t0).
        for (int t = tstart; t < t0; ++t) {
            const float x = features[(size_t)t * (BB * FF) + b * FF + f];
            #pragma unroll
            for (int j = 0; j < 4; ++j)
                s[j] = fmaf(lam[j], s[j], onem[j] * x);
        }
    }

    // ---- Main chunk: scan + write every step ----
    const float* fptr = features + (size_t)t0 * (BB * FF) + b * FF + f;
    const int*   rptr = resets + (size_t)t0 * BB + b;
    f32x4*       yptr = out4 + NGROUP + (size_t)t0 * NGROUP + g;

    #pragma unroll
    for (int t = 0; t < TC; ++t) {
        const float x = fptr[(size_t)t * (BB * FF)];
        const int   r = rptr[(size_t)t * BB];
        #pragma unroll
        for (int j = 0; j < 4; ++j) {
            const float v = fmaf(lam[j], s[j], onem[j] * x);
            s[j] = r ? x : v;
        }
        __builtin_nontemporal_store(s, yptr + (size_t)t * NGROUP);
    }

    // final_trace (FIRST output in the concatenation)
    if (chunk == NCHUNK - 1) out4[g] = s;
}

extern "C" void kernel_launch(void* const* d_in, const int* in_sizes, int n_in,
                              void* d_out, int out_size, void* d_ws, size_t ws_size,
                              hipStream_t stream) {
    const float* features = (const float*)d_in[0];
    const int*   resets   = (const int*)d_in[1];
    const float* carry    = (const float*)d_in[2];
    const float* lambdas  = (const float*)d_in[3];
    f32x4* out4 = (f32x4*)d_out;

    const int grid = NCHUNK * 64;  // 2048 blocks, 8/CU, 32 waves/CU
    trace_rnn_lookback<<<grid, 256, 0, stream>>>(
        features, resets, carry, lambdas, out4);
}